// Round 16
// baseline (412.319 us; speedup 1.0000x reference)
//
#include <hip/hip_runtime.h>
#include <cstdint>

// AnchorTargetLayer: T = 160*160*9 anchors vs M = 128 gt boxes.
// Output (T,7): [label, t0..t3, inside_w, outside_w], float32, row-major.

#define T_TOTAL 230400
#define W_ 160
#define A_ 9
#define M_ 128
#define NB_ 900      // sweep blocks (900*256 == T_TOTAL)
#define NBINS 4096
#define BCAP 1024
#define KFG 128
#define BATCH 256
#define SSTR 17      // LDS column-max copy stride (16 copies + 1 pad: bank-spread)

struct Ws {
  int gt_max_bits[M_];        // float bits of per-gt max IoU (written by k_reduce)
  float4 g_box[M_];           // {x1,y1,x2,y2}
  float g_area[M_];
  float amm[4];               // min x1, min y1, max x2, max y2 over the 9 base anchors
  int fg_count, bg_count;     // written by k_select (derived from hist sums)
  int sel_fg, b_fg, cb_fg;    // selection-needed flag, boundary bucket, count-before
  int sel_bg, b_bg, cb_bg, k_bg;
  float cut_fg_val; int cut_fg_idx;
  float cut_bg_val; int cut_bg_idx;
  float wgt;
  int hist_fg[NBINS], hist_bg[NBINS];
  unsigned char lab8[T_TOTAL];   // 0 = ignore(-1), 1 = bg(0), 2 = fg(1)
  float t_soa[4][T_TOTAL];       // bbox targets, SoA (coalesced)
  int blk_max[NB_ * M_];         // per-block per-gt max IoU bits (no atomics)
};

// Strict IEEE fp32 ops, no contraction — must match numpy/XLA rounding exactly.
__device__ __forceinline__ float fA(float a, float b) { return __fadd_rn(a, b); }
__device__ __forceinline__ float fS(float a, float b) { return __fsub_rn(a, b); }
__device__ __forceinline__ float fM(float a, float b) { return __fmul_rn(a, b); }
__device__ __forceinline__ float fD(float a, float b) { return __fdiv_rn(a, b); }

__device__ __forceinline__ int bucket_of(float v) {
  int b = (int)(v * 4096.0f);
  return b > (NBINS - 1) ? (NBINS - 1) : (b < 0 ? 0 : b);
}

// Recompute anchor geometry for thread's anchor i (bit-exact vs reference).
__device__ __forceinline__ void anchor_coords(int i, const float* anch, float fs,
                                              float& ax1, float& ay1, float& ax2, float& ay2) {
  int s = i / A_, a = i - s * A_;
  int x = s % W_, y = s / W_;
  float shx = fM((float)x, fs), shy = fM((float)y, fs);
  ax1 = fA(anch[a * 4 + 0], shx);
  ay1 = fA(anch[a * 4 + 1], shy);
  ax2 = fA(anch[a * 4 + 2], shx);
  ay2 = fA(anch[a * 4 + 3], shy);
}

// Conservative bbox of this wave's 64 anchors (clipped to image).
// Used only for culling; culled pairs have exactly ov==0 so skipping is exact.
__device__ __forceinline__ void wave_bbox(int i0, const float* amm, float fs,
                                          float imw, float imh,
                                          float& wx1, float& wy1, float& wx2, float& wy2) {
  int s_lo = i0 / A_, s_hi = (i0 + 63) / A_;
  int y_lo = s_lo / W_, y_hi = s_hi / W_;
  int x_lo = s_lo - y_lo * W_, x_hi = s_hi - y_hi * W_;
  if (y_lo != y_hi) { x_lo = 0; x_hi = W_ - 1; }  // row wrap: conservative
  wx1 = fmaxf(amm[0] + fM((float)x_lo, fs), 0.0f);
  wy1 = fmaxf(amm[1] + fM((float)y_lo, fs), 0.0f);
  wx2 = fminf(amm[2] + fM((float)x_hi, fs), imw);
  wy2 = fminf(amm[3] + fM((float)y_hi, fs), imh);
}

__global__ __launch_bounds__(256) void k_init(const float* gt, const float* anch, Ws* ws) {
  int t = blockIdx.x * blockDim.x + threadIdx.x;
  int n = gridDim.x * blockDim.x;
  for (int i = t; i < NBINS; i += n) { ws->hist_fg[i] = 0; ws->hist_bg[i] = 0; }
  if (t < M_) {
    float x1 = gt[t * 5 + 0], y1 = gt[t * 5 + 1];
    float x2 = gt[t * 5 + 2], y2 = gt[t * 5 + 3];
    ws->g_box[t] = make_float4(x1, y1, x2, y2);
    ws->g_area[t] = fM(fA(fS(x2, x1), 1.0f), fA(fS(y2, y1), 1.0f));
  }
  if (t == 0) {
    float mx1 = anch[0], my1 = anch[1], Mx2 = anch[2], My2 = anch[3];
    for (int a = 1; a < A_; ++a) {
      mx1 = fminf(mx1, anch[a * 4 + 0]);
      my1 = fminf(my1, anch[a * 4 + 1]);
      Mx2 = fmaxf(Mx2, anch[a * 4 + 2]);
      My2 = fmaxf(My2, anch[a * 4 + 3]);
    }
    ws->amm[0] = mx1; ws->amm[1] = my1; ws->amm[2] = Mx2; ws->amm[3] = My2;
    ws->fg_count = 0; ws->bg_count = 0;
    ws->cut_fg_val = 2.0f; ws->cut_fg_idx = 0x7fffffff;
    ws->cut_bg_val = 2.0f; ws->cut_bg_idx = 0x7fffffff;
  }
}

// Fused sweep (R15): row max/argmax + column max via bank-spread predicated LDS
// atomics; writes targets, the PRELIMINARY labels (bg / fg-threshold; is_best
// patched by k_fixup), and the preliminary histograms. Per-block column maxima
// out as one coalesced store.
__global__ __launch_bounds__(256) void k_sweep(
    const float4* __restrict__ gbox, const float* __restrict__ gap,
    const float* __restrict__ amm,
    const float* im_info, const float* anchors, const int* fsp,
    const float* rand_fg, const float* rand_bg,
    int* __restrict__ blk_max, Ws* ws) {
  __shared__ int smax[M_ * SSTR];
  int tid = threadIdx.x;
  for (int s = tid; s < M_ * SSTR; s += 256) smax[s] = 0;
  __syncthreads();

  int lane = tid & 63, wv = tid >> 6;
  int slot = lane & 15;
  int i = blockIdx.x * 256 + tid;  // grid exactly covers T_TOTAL (900*256)
  float fs = (float)fsp[0];
  float imh = im_info[0], imw = im_info[1];
  float rx1, ry1, rx2, ry2;
  anchor_coords(i, anchors, fs, rx1, ry1, rx2, ry2);
  bool inside = (rx1 >= 0.0f) && (ry1 >= 0.0f) && (rx2 < imw) && (ry2 < imh);
  float ax1 = rx1, ay1 = ry1, ax2 = rx2, ay2 = ry2, aarea;
  if (inside) {
    aarea = fM(fA(fS(ax2, ax1), 1.0f), fA(fS(ay2, ay1), 1.0f));
  } else {  // fake degenerate box: never intersects, ov stays 0
    ax1 = 0.0f; ay1 = 0.0f; ax2 = -2.0f; ay2 = -2.0f; aarea = 1.0f;
  }

  float wx1, wy1, wx2, wy2;
  wave_bbox(blockIdx.x * 256 + wv * 64, amm, fs, imw, imh, wx1, wy1, wx2, wy2);
  float4 gA = gbox[lane];
  float4 gB = gbox[lane + 64];
  bool cA = (gA.x <= wx2 + 1.0f) && (gA.z + 1.0f >= wx1) &&
            (gA.y <= wy2 + 1.0f) && (gA.w + 1.0f >= wy1);
  bool cB = (gB.x <= wx2 + 1.0f) && (gB.z + 1.0f >= wx1) &&
            (gB.y <= wy2 + 1.0f) && (gB.w + 1.0f >= wy1);
  unsigned long long m0 = __ballot(cA);
  unsigned long long m1 = __ballot(cB);

  float bestv = 0.0f;  // non-candidate / zero rows -> argmax = 0 (matches reference)
  int bestj = 0;
  auto body = [&](int j) {
    float4 g = gbox[j];  // uniform j -> scalar load
    float iw = fA(fS(fminf(ax2, g.z), fmaxf(ax1, g.x)), 1.0f);
    float ih = fA(fS(fminf(ay2, g.w), fmaxf(ay1, g.y)), 1.0f);
    float inter = fM(fmaxf(iw, 0.0f), fmaxf(ih, 0.0f));
    float uni = fS(fA(aarea, gap[j]), inter);
    float ov = fD(inter, uni);  // non-hit lanes: exact 0.0f
    if (ov > bestv) { bestv = ov; bestj = j; }  // strict >, j ascending == first-index argmax
    if (ov > 0.0f) atomicMax(&smax[j * SSTR + slot], __float_as_int(ov));  // ds_max, no chain
  };
  while (m0) { int j = __ffsll(m0) - 1; m0 &= (m0 - 1); body(j); }
  while (m1) { int j = __ffsll(m1) + 63; m1 &= (m1 - 1); body(j); }

  // Preliminary labels (reference steps: bg, then fg-threshold; is_best — which
  // also sets 1 and commutes with the >=0.7 step — is patched in k_fixup).
  float lab = -1.0f;
  if (inside && bestv < 0.3f) lab = 0.0f;
  if (inside && bestv >= 0.7f) lab = 1.0f;

  float t0 = 0.0f, t1 = 0.0f, t2 = 0.0f, t3 = 0.0f;
  if (inside) {  // reference op order
    float ew = fA(fS(rx2, rx1), 1.0f), eh = fA(fS(ry2, ry1), 1.0f);
    float ecx = fA(rx1, fM(0.5f, ew)), ecy = fA(ry1, fM(0.5f, eh));
    float4 g = gbox[bestj];  // divergent: one global_load_dwordx4
    float gw = fA(fS(g.z, g.x), 1.0f), gh = fA(fS(g.w, g.y), 1.0f);
    float gcx = fA(g.x, fM(0.5f, gw)), gcy = fA(g.y, fM(0.5f, gh));
    t0 = fD(fS(gcx, ecx), ew);
    t1 = fD(fS(gcy, ecy), eh);
    t2 = logf(fD(gw, ew));
    t3 = logf(fD(gh, eh));
  }

  // Coalesced SoA writes only.
  ws->lab8[i] = lab == 1.0f ? 2 : (lab == 0.0f ? 1 : 0);
  ws->t_soa[0][i] = t0;
  ws->t_soa[1][i] = t1;
  ws->t_soa[2][i] = t2;
  ws->t_soa[3][i] = t3;
  if (lab == 1.0f) atomicAdd(&ws->hist_fg[bucket_of(rand_fg[i])], 1);
  if (lab == 0.0f) atomicAdd(&ws->hist_bg[bucket_of(rand_bg[i])], 1);

  __syncthreads();
  if (tid < M_) {
    int m = 0;
#pragma unroll
    for (int s = 0; s < 16; ++s) {           // stride-17 rows -> conflict-light
      int v = smax[tid * SSTR + s];
      m = v > m ? v : m;
    }
    blk_max[blockIdx.x * M_ + tid] = m;      // coalesced, no atomics
  }
}

// Column reduce: gmb[j] = max over 900 blocks of blk_max[b][j]. All values are
// non-negative float bits, so int max == float max. One wave per gt.
__global__ __launch_bounds__(64) void k_reduce(const int* __restrict__ blk_max, int* gmb) {
  int j = blockIdx.x;       // 0..127
  int lane = threadIdx.x;   // 0..63
  int m = 0;
  for (int b = lane; b < NB_; b += 64) {
    int v = blk_max[b * M_ + j];
    m = v > m ? v : m;
  }
  m = max(m, __shfl_xor(m, 1));
  m = max(m, __shfl_xor(m, 2));
  m = max(m, __shfl_xor(m, 4));
  m = max(m, __shfl_xor(m, 8));
  m = max(m, __shfl_xor(m, 16));
  m = max(m, __shfl_xor(m, 32));
  if (lane == 0) gmb[j] = m;
}

// is_best fixup: a block can contain an is_best anchor for gt j ONLY if its
// block max equals the global max (necessary: ov==gt_max forces blk_max==gmb).
// ~85% of blocks have no flagged gt and exit after 128 compares. Flagged
// blocks recompute ov vs the (few) flagged gts for their 256 anchors and
// promote matches to fg, patching the histograms (is_best sets 1 after the
// bg step and commutes with the >=0.7 step -> promote-if-not-already-fg).
__global__ __launch_bounds__(256) void k_fixup(
    const float4* __restrict__ gbox, const float* __restrict__ gap,
    const int* __restrict__ gmb, const int* __restrict__ blk_max,
    const float* im_info, const float* anchors, const int* fsp,
    const float* rand_fg, const float* rand_bg, Ws* ws) {
  __shared__ int fl[M_];
  __shared__ int nfl;
  int tid = threadIdx.x;
  if (tid == 0) nfl = 0;
  __syncthreads();
  const int* bmrow = blk_max + blockIdx.x * M_;
  if (tid < M_) {
    int gm = gmb[tid];
    if (gm > 0 && bmrow[tid] == gm) fl[atomicAdd(&nfl, 1)] = tid;
  }
  __syncthreads();
  int n = nfl;
  if (n == 0) return;

  int i = blockIdx.x * 256 + tid;
  float fs = (float)fsp[0];
  float imh = im_info[0], imw = im_info[1];
  float ax1, ay1, ax2, ay2;
  anchor_coords(i, anchors, fs, ax1, ay1, ax2, ay2);
  bool inside = (ax1 >= 0.0f) && (ay1 >= 0.0f) && (ax2 < imw) && (ay2 < imh);
  float aarea;
  if (inside) {
    aarea = fM(fA(fS(ax2, ax1), 1.0f), fA(fS(ay2, ay1), 1.0f));
  } else {
    ax1 = 0.0f; ay1 = 0.0f; ax2 = -2.0f; ay2 = -2.0f; aarea = 1.0f;
  }
  bool isbest = false;
  for (int k = 0; k < n; ++k) {
    int j = fl[k];           // LDS broadcast (order irrelevant: OR semantics)
    float4 g = gbox[j];
    float iw = fA(fS(fminf(ax2, g.z), fmaxf(ax1, g.x)), 1.0f);
    float ih = fA(fS(fminf(ay2, g.w), fmaxf(ay1, g.y)), 1.0f);
    float inter = fM(fmaxf(iw, 0.0f), fmaxf(ih, 0.0f));
    float uni = fS(fA(aarea, gap[j]), inter);
    float ov = fD(inter, uni);
    if (__float_as_int(ov) == gmb[j]) isbest = true;  // gt_max > 0, ov=0 never matches
  }
  if (isbest && inside) {  // outside rows are -1 in ref, never equal gt_max > 0
    int old = ws->lab8[i];
    if (old != 2) {
      ws->lab8[i] = 2;
      atomicAdd(&ws->hist_fg[bucket_of(rand_fg[i])], 1);
      if (old == 1) atomicSub(&ws->hist_bg[bucket_of(rand_bg[i])], 1);
    }
  }
}

// Fused selection tail (was k_scan + k_collect + k_cut), one block:
// phase 1: histogram scan -> sel/bucket/count-before (LDS);
// phase 2: collect boundary-bucket (value,index) pairs into LDS (coalesced
//          pass over lab8; append order irrelevant — phase 3 ranks exactly);
// phase 3: exact lexicographic rank cut from LDS;
// phase 4: publish sel/b/cut/wgt to ws for k_final.
__global__ __launch_bounds__(256) void k_select(const float* __restrict__ rand_fg,
                                                const float* __restrict__ rand_bg,
                                                Ws* ws) {
  __shared__ int part[256];
  __shared__ int s_fgc, s_bgc, s_kbg;
  __shared__ int s_sel[2], s_b[2], s_cb[2];
  __shared__ float sv[2][BCAP];
  __shared__ int   si[2][BCAP];
  __shared__ int   sn[2];
  int tid = threadIdx.x;
  if (tid < 2) sn[tid] = 0;

  // Phase 1: scan (identical arithmetic to the old k_scan)
  for (int pass = 0; pass < 2; ++pass) {
    const int* hist = pass == 0 ? ws->hist_fg : ws->hist_bg;
    int sum = 0;
    for (int b = 0; b < NBINS / 256; ++b) sum += hist[tid * (NBINS / 256) + b];
    part[tid] = sum;
    __syncthreads();
    if (tid == 0) {
      int cnt = 0;
      for (int c = 0; c < 256; ++c) cnt += part[c];
      int k, kbg = 0;
      if (pass == 0) { s_fgc = cnt; k = KFG; }
      else {
        s_bgc = cnt;
        int kept_fg = s_fgc < KFG ? s_fgc : KFG;
        kbg = BATCH - kept_fg;
        k = kbg;
      }
      if (cnt > k) {  // selection needed; cutoff element is the k-th (0-indexed)
        int cum = 0, chunk = 0;
        for (int c = 0; c < 256; ++c) {
          if (cum + part[c] >= k + 1) { chunk = c; break; }
          cum += part[c];
        }
        int b = chunk * (NBINS / 256);
        for (int bb = chunk * (NBINS / 256); bb < (chunk + 1) * (NBINS / 256); ++bb) {
          if (cum + hist[bb] >= k + 1) { b = bb; break; }
          cum += hist[bb];
        }
        s_sel[pass] = 1; s_b[pass] = b; s_cb[pass] = cum;
      } else {
        s_sel[pass] = 0; s_b[pass] = -1; s_cb[pass] = 0;
      }
      if (pass == 1) s_kbg = kbg;
    }
    __syncthreads();
  }

  // Phase 2: collect boundary elements into LDS (coalesced lab8 pass)
  int selF = s_sel[0], selB = s_sel[1];
  int bF = s_b[0], bB = s_b[1];
  if (selF || selB) {
    for (int i = tid; i < T_TOTAL; i += 256) {
      int code = ws->lab8[i];
      if (code == 2 && selF) {
        float v = rand_fg[i];
        if (bucket_of(v) == bF) {
          int p = atomicAdd(&sn[0], 1);
          if (p < BCAP) { sv[0][p] = v; si[0][p] = i; }
        }
      }
      if (code == 1 && selB) {
        float v = rand_bg[i];
        if (bucket_of(v) == bB) {
          int p = atomicAdd(&sn[1], 1);
          if (p < BCAP) { sv[1][p] = v; si[1][p] = i; }
        }
      }
    }
  }
  __syncthreads();

  // Phase 3: exact r-th smallest (value, index) pair within each boundary bucket
  for (int pass = 0; pass < 2; ++pass) {
    if (s_sel[pass]) {
      int n = sn[pass] < BCAP ? sn[pass] : BCAP;
      int r = pass == 0 ? (KFG - s_cb[0]) : (s_kbg - s_cb[1]);
      if (r >= 0 && r < n) {
        for (int e = tid; e < n; e += 256) {
          float ve = sv[pass][e]; int ie = si[pass][e];
          int c = 0;
          for (int o = 0; o < n; ++o) {
            float vo = sv[pass][o]; int io = si[pass][o];
            if (vo < ve || (vo == ve && io < ie)) c++;
          }
          if (c == r) {  // exactly one element has lexicographic rank r
            if (pass == 0) { ws->cut_fg_val = ve; ws->cut_fg_idx = ie; }
            else           { ws->cut_bg_val = ve; ws->cut_bg_idx = ie; }
          }
        }
      }
    }
  }
  __syncthreads();

  // Phase 4: publish
  if (tid == 0) {
    ws->fg_count = s_fgc; ws->bg_count = s_bgc;
    ws->sel_fg = s_sel[0]; ws->b_fg = s_b[0]; ws->cb_fg = s_cb[0];
    ws->sel_bg = s_sel[1]; ws->b_bg = s_b[1]; ws->cb_bg = s_cb[1];
    ws->k_bg = s_kbg;
    int kept_fg = s_sel[0] ? KFG : s_fgc;
    int kept_bg = s_sel[1] ? s_kbg : s_bgc;
    int ne = kept_fg + kept_bg;
    ws->wgt = (ne > 0) ? __fdiv_rn(1.0f, (float)(ne < 1 ? 1 : ne)) : 0.0f;
  }
}

// Apply subsampling cutoffs; assemble all 7 output columns and write the
// (T,7) AoS rows via LDS transpose -> 7 fully-coalesced wave stores per block.
__global__ __launch_bounds__(256) void k_final(const float* rand_fg, const float* rand_bg,
                                               const Ws* __restrict__ ws, float* out) {
  __shared__ float sh[256][8];  // +1 pad col to break bank alignment
  int tid = threadIdx.x;
  int i0 = blockIdx.x * 256;
  int i = i0 + tid;
  int code = ws->lab8[i];
  float lab = code == 2 ? 1.0f : (code == 1 ? 0.0f : -1.0f);
  if (code == 2 && ws->sel_fg) {
    float v = rand_fg[i];
    int b = bucket_of(v);
    float cv = ws->cut_fg_val; int ci = ws->cut_fg_idx;
    bool keep = (b < ws->b_fg) ||
                (b == ws->b_fg && (v < cv || (v == cv && i < ci)));
    if (!keep) lab = -1.0f;
  }
  if (code == 1 && ws->sel_bg) {
    float v = rand_bg[i];
    int b = bucket_of(v);
    float cv = ws->cut_bg_val; int ci = ws->cut_bg_idx;
    bool keep = (b < ws->b_bg) ||
                (b == ws->b_bg && (v < cv || (v == cv && i < ci)));
    if (!keep) lab = -1.0f;
  }
  sh[tid][0] = lab;
  sh[tid][1] = ws->t_soa[0][i];
  sh[tid][2] = ws->t_soa[1][i];
  sh[tid][3] = ws->t_soa[2][i];
  sh[tid][4] = ws->t_soa[3][i];
  sh[tid][5] = (lab == 1.0f) ? 1.0f : 0.0f;
  sh[tid][6] = (lab >= 0.0f) ? ws->wgt : 0.0f;
  __syncthreads();
#pragma unroll
  for (int k = 0; k < 7; ++k) {
    int l = k * 256 + tid;
    out[i0 * 7 + l] = sh[l / 7][l % 7];
  }
}

extern "C" void kernel_launch(void* const* d_in, const int* in_sizes, int n_in,
                              void* d_out, int out_size, void* d_ws, size_t ws_size,
                              hipStream_t stream) {
  const float* gt   = (const float*)d_in[1];
  const float* im   = (const float*)d_in[2];
  const float* anch = (const float*)d_in[3];
  const float* rfg  = (const float*)d_in[4];
  const float* rbg  = (const float*)d_in[5];
  const int*   fs   = (const int*)d_in[6];
  float* out = (float*)d_out;
  Ws* ws = (Ws*)d_ws;

  dim3 blk(256);
  k_init<<<17, blk, 0, stream>>>(gt, anch, ws);
  k_sweep<<<NB_, blk, 0, stream>>>(ws->g_box, ws->g_area, ws->amm, im, anch, fs,
                                   rfg, rbg, ws->blk_max, ws);
  k_reduce<<<M_, 64, 0, stream>>>(ws->blk_max, ws->gt_max_bits);
  k_fixup<<<NB_, blk, 0, stream>>>(ws->g_box, ws->g_area, ws->gt_max_bits, ws->blk_max,
                                   im, anch, fs, rfg, rbg, ws);
  k_select<<<1, blk, 0, stream>>>(rfg, rbg, ws);
  k_final<<<NB_, blk, 0, stream>>>(rfg, rbg, ws, out);
}

// Round 17
// 50.861 us; speedup vs baseline: 8.1068x; 8.1068x over previous
//
#include <hip/hip_runtime.h>
#include <cstdint>

// AnchorTargetLayer: T = 160*160*9 anchors vs M = 128 gt boxes.
// Output (T,7): [label, t0..t3, inside_w, outside_w], float32, row-major.

#define T_TOTAL 230400
#define W_ 160
#define A_ 9
#define M_ 128
#define NB_ 900      // sweep blocks (900*256 == T_TOTAL)
#define NBINS 4096
#define BCAP 1024
#define KFG 128
#define BATCH 256
#define SSTR 17      // LDS column-max copy stride (16 copies + 1 pad: bank-spread)

struct Ws {
  int gt_max_bits[M_];        // float bits of per-gt max IoU (written by k_reduce)
  float4 g_box[M_];           // {x1,y1,x2,y2}
  float g_area[M_];
  float amm[4];               // min x1, min y1, max x2, max y2 over the 9 base anchors
  int fg_count, bg_count;     // written by k_scan (derived from hist sums)
  int bnd_fg_n, bnd_bg_n;
  int sel_fg, b_fg, cb_fg;    // selection-needed flag, boundary bucket, count-before
  int sel_bg, b_bg, cb_bg, k_bg;
  float cut_fg_val; int cut_fg_idx;
  float cut_bg_val; int cut_bg_idx;
  float wgt;
  int hist_fg[NBINS], hist_bg[NBINS];
  float bnd_fg_val[BCAP]; int bnd_fg_idx[BCAP];
  float bnd_bg_val[BCAP]; int bnd_bg_idx[BCAP];
  unsigned char lab8[T_TOTAL];   // 0 = ignore(-1), 1 = bg(0), 2 = fg(1)
  float t_soa[4][T_TOTAL];       // bbox targets, SoA (coalesced)
  int blk_max[NB_ * M_];         // per-block per-gt max IoU bits (no atomics)
};

// Strict IEEE fp32 ops, no contraction — must match numpy/XLA rounding exactly.
__device__ __forceinline__ float fA(float a, float b) { return __fadd_rn(a, b); }
__device__ __forceinline__ float fS(float a, float b) { return __fsub_rn(a, b); }
__device__ __forceinline__ float fM(float a, float b) { return __fmul_rn(a, b); }
__device__ __forceinline__ float fD(float a, float b) { return __fdiv_rn(a, b); }

__device__ __forceinline__ int bucket_of(float v) {
  int b = (int)(v * 4096.0f);
  return b > (NBINS - 1) ? (NBINS - 1) : (b < 0 ? 0 : b);
}

// Recompute anchor geometry for thread's anchor i (bit-exact vs reference).
__device__ __forceinline__ void anchor_coords(int i, const float* anch, float fs,
                                              float& ax1, float& ay1, float& ax2, float& ay2) {
  int s = i / A_, a = i - s * A_;
  int x = s % W_, y = s / W_;
  float shx = fM((float)x, fs), shy = fM((float)y, fs);
  ax1 = fA(anch[a * 4 + 0], shx);
  ay1 = fA(anch[a * 4 + 1], shy);
  ax2 = fA(anch[a * 4 + 2], shx);
  ay2 = fA(anch[a * 4 + 3], shy);
}

// Conservative bbox of this wave's 64 anchors (clipped to image).
// Used only for culling; culled pairs have exactly ov==0 so skipping is exact.
__device__ __forceinline__ void wave_bbox(int i0, const float* amm, float fs,
                                          float imw, float imh,
                                          float& wx1, float& wy1, float& wx2, float& wy2) {
  int s_lo = i0 / A_, s_hi = (i0 + 63) / A_;
  int y_lo = s_lo / W_, y_hi = s_hi / W_;
  int x_lo = s_lo - y_lo * W_, x_hi = s_hi - y_hi * W_;
  if (y_lo != y_hi) { x_lo = 0; x_hi = W_ - 1; }  // row wrap: conservative
  wx1 = fmaxf(amm[0] + fM((float)x_lo, fs), 0.0f);
  wy1 = fmaxf(amm[1] + fM((float)y_lo, fs), 0.0f);
  wx2 = fminf(amm[2] + fM((float)x_hi, fs), imw);
  wy2 = fminf(amm[3] + fM((float)y_hi, fs), imh);
}

__global__ __launch_bounds__(256) void k_init(const float* gt, const float* anch, Ws* ws) {
  int t = blockIdx.x * blockDim.x + threadIdx.x;
  int n = gridDim.x * blockDim.x;
  for (int i = t; i < NBINS; i += n) { ws->hist_fg[i] = 0; ws->hist_bg[i] = 0; }
  if (t < M_) {
    float x1 = gt[t * 5 + 0], y1 = gt[t * 5 + 1];
    float x2 = gt[t * 5 + 2], y2 = gt[t * 5 + 3];
    ws->g_box[t] = make_float4(x1, y1, x2, y2);
    ws->g_area[t] = fM(fA(fS(x2, x1), 1.0f), fA(fS(y2, y1), 1.0f));
  }
  if (t == 0) {
    float mx1 = anch[0], my1 = anch[1], Mx2 = anch[2], My2 = anch[3];
    for (int a = 1; a < A_; ++a) {
      mx1 = fminf(mx1, anch[a * 4 + 0]);
      my1 = fminf(my1, anch[a * 4 + 1]);
      Mx2 = fmaxf(Mx2, anch[a * 4 + 2]);
      My2 = fmaxf(My2, anch[a * 4 + 3]);
    }
    ws->amm[0] = mx1; ws->amm[1] = my1; ws->amm[2] = Mx2; ws->amm[3] = My2;
    ws->fg_count = 0; ws->bg_count = 0;
    ws->bnd_fg_n = 0; ws->bnd_bg_n = 0;
    ws->cut_fg_val = 2.0f; ws->cut_fg_idx = 0x7fffffff;
    ws->cut_bg_val = 2.0f; ws->cut_bg_idx = 0x7fffffff;
  }
}

// Fused sweep (R15): row max/argmax + column max via bank-spread predicated LDS
// atomics; writes targets, the PRELIMINARY labels (bg / fg-threshold; is_best
// patched by k_fixup), and the preliminary histograms. Per-block column maxima
// out as one coalesced store.
__global__ __launch_bounds__(256) void k_sweep(
    const float4* __restrict__ gbox, const float* __restrict__ gap,
    const float* __restrict__ amm,
    const float* im_info, const float* anchors, const int* fsp,
    const float* rand_fg, const float* rand_bg,
    int* __restrict__ blk_max, Ws* ws) {
  __shared__ int smax[M_ * SSTR];
  int tid = threadIdx.x;
  for (int s = tid; s < M_ * SSTR; s += 256) smax[s] = 0;
  __syncthreads();

  int lane = tid & 63, wv = tid >> 6;
  int slot = lane & 15;
  int i = blockIdx.x * 256 + tid;  // grid exactly covers T_TOTAL (900*256)
  float fs = (float)fsp[0];
  float imh = im_info[0], imw = im_info[1];
  float rx1, ry1, rx2, ry2;
  anchor_coords(i, anchors, fs, rx1, ry1, rx2, ry2);
  bool inside = (rx1 >= 0.0f) && (ry1 >= 0.0f) && (rx2 < imw) && (ry2 < imh);
  float ax1 = rx1, ay1 = ry1, ax2 = rx2, ay2 = ry2, aarea;
  if (inside) {
    aarea = fM(fA(fS(ax2, ax1), 1.0f), fA(fS(ay2, ay1), 1.0f));
  } else {  // fake degenerate box: never intersects, ov stays 0
    ax1 = 0.0f; ay1 = 0.0f; ax2 = -2.0f; ay2 = -2.0f; aarea = 1.0f;
  }

  float wx1, wy1, wx2, wy2;
  wave_bbox(blockIdx.x * 256 + wv * 64, amm, fs, imw, imh, wx1, wy1, wx2, wy2);
  float4 gA = gbox[lane];
  float4 gB = gbox[lane + 64];
  bool cA = (gA.x <= wx2 + 1.0f) && (gA.z + 1.0f >= wx1) &&
            (gA.y <= wy2 + 1.0f) && (gA.w + 1.0f >= wy1);
  bool cB = (gB.x <= wx2 + 1.0f) && (gB.z + 1.0f >= wx1) &&
            (gB.y <= wy2 + 1.0f) && (gB.w + 1.0f >= wy1);
  unsigned long long m0 = __ballot(cA);
  unsigned long long m1 = __ballot(cB);

  float bestv = 0.0f;  // non-candidate / zero rows -> argmax = 0 (matches reference)
  int bestj = 0;
  auto body = [&](int j) {
    float4 g = gbox[j];  // uniform j -> scalar load
    float iw = fA(fS(fminf(ax2, g.z), fmaxf(ax1, g.x)), 1.0f);
    float ih = fA(fS(fminf(ay2, g.w), fmaxf(ay1, g.y)), 1.0f);
    float inter = fM(fmaxf(iw, 0.0f), fmaxf(ih, 0.0f));
    float uni = fS(fA(aarea, gap[j]), inter);
    float ov = fD(inter, uni);  // non-hit lanes: exact 0.0f
    if (ov > bestv) { bestv = ov; bestj = j; }  // strict >, j ascending == first-index argmax
    if (ov > 0.0f) atomicMax(&smax[j * SSTR + slot], __float_as_int(ov));  // ds_max, no chain
  };
  while (m0) { int j = __ffsll(m0) - 1; m0 &= (m0 - 1); body(j); }
  while (m1) { int j = __ffsll(m1) + 63; m1 &= (m1 - 1); body(j); }

  // Preliminary labels (reference steps: bg, then fg-threshold; is_best — which
  // also sets 1 and commutes with the >=0.7 step — is patched in k_fixup).
  float lab = -1.0f;
  if (inside && bestv < 0.3f) lab = 0.0f;
  if (inside && bestv >= 0.7f) lab = 1.0f;

  float t0 = 0.0f, t1 = 0.0f, t2 = 0.0f, t3 = 0.0f;
  if (inside) {  // reference op order
    float ew = fA(fS(rx2, rx1), 1.0f), eh = fA(fS(ry2, ry1), 1.0f);
    float ecx = fA(rx1, fM(0.5f, ew)), ecy = fA(ry1, fM(0.5f, eh));
    float4 g = gbox[bestj];  // divergent: one global_load_dwordx4
    float gw = fA(fS(g.z, g.x), 1.0f), gh = fA(fS(g.w, g.y), 1.0f);
    float gcx = fA(g.x, fM(0.5f, gw)), gcy = fA(g.y, fM(0.5f, gh));
    t0 = fD(fS(gcx, ecx), ew);
    t1 = fD(fS(gcy, ecy), eh);
    t2 = logf(fD(gw, ew));
    t3 = logf(fD(gh, eh));
  }

  // Coalesced SoA writes only.
  ws->lab8[i] = lab == 1.0f ? 2 : (lab == 0.0f ? 1 : 0);
  ws->t_soa[0][i] = t0;
  ws->t_soa[1][i] = t1;
  ws->t_soa[2][i] = t2;
  ws->t_soa[3][i] = t3;
  if (lab == 1.0f) atomicAdd(&ws->hist_fg[bucket_of(rand_fg[i])], 1);
  if (lab == 0.0f) atomicAdd(&ws->hist_bg[bucket_of(rand_bg[i])], 1);

  __syncthreads();
  if (tid < M_) {
    int m = 0;
#pragma unroll
    for (int s = 0; s < 16; ++s) {           // stride-17 rows -> conflict-light
      int v = smax[tid * SSTR + s];
      m = v > m ? v : m;
    }
    blk_max[blockIdx.x * M_ + tid] = m;      // coalesced, no atomics
  }
}

// Column reduce: gmb[j] = max over 900 blocks of blk_max[b][j]. All values are
// non-negative float bits, so int max == float max. One wave per gt.
__global__ __launch_bounds__(64) void k_reduce(const int* __restrict__ blk_max, int* gmb) {
  int j = blockIdx.x;       // 0..127
  int lane = threadIdx.x;   // 0..63
  int m = 0;
  for (int b = lane; b < NB_; b += 64) {
    int v = blk_max[b * M_ + j];
    m = v > m ? v : m;
  }
  m = max(m, __shfl_xor(m, 1));
  m = max(m, __shfl_xor(m, 2));
  m = max(m, __shfl_xor(m, 4));
  m = max(m, __shfl_xor(m, 8));
  m = max(m, __shfl_xor(m, 16));
  m = max(m, __shfl_xor(m, 32));
  if (lane == 0) gmb[j] = m;
}

// is_best fixup: a block can contain an is_best anchor for gt j ONLY if its
// block max equals the global max (necessary: ov==gt_max forces blk_max==gmb).
// ~85% of blocks have no flagged gt and exit after 128 compares. Flagged
// blocks recompute ov vs the (few) flagged gts for their 256 anchors and
// promote matches to fg, patching the histograms (is_best sets 1 after the
// bg step and commutes with the >=0.7 step -> promote-if-not-already-fg).
__global__ __launch_bounds__(256) void k_fixup(
    const float4* __restrict__ gbox, const float* __restrict__ gap,
    const int* __restrict__ gmb, const int* __restrict__ blk_max,
    const float* im_info, const float* anchors, const int* fsp,
    const float* rand_fg, const float* rand_bg, Ws* ws) {
  __shared__ int fl[M_];
  __shared__ int nfl;
  int tid = threadIdx.x;
  if (tid == 0) nfl = 0;
  __syncthreads();
  const int* bmrow = blk_max + blockIdx.x * M_;
  if (tid < M_) {
    int gm = gmb[tid];
    if (gm > 0 && bmrow[tid] == gm) fl[atomicAdd(&nfl, 1)] = tid;
  }
  __syncthreads();
  int n = nfl;
  if (n == 0) return;

  int i = blockIdx.x * 256 + tid;
  float fs = (float)fsp[0];
  float imh = im_info[0], imw = im_info[1];
  float ax1, ay1, ax2, ay2;
  anchor_coords(i, anchors, fs, ax1, ay1, ax2, ay2);
  bool inside = (ax1 >= 0.0f) && (ay1 >= 0.0f) && (ax2 < imw) && (ay2 < imh);
  float aarea;
  if (inside) {
    aarea = fM(fA(fS(ax2, ax1), 1.0f), fA(fS(ay2, ay1), 1.0f));
  } else {
    ax1 = 0.0f; ay1 = 0.0f; ax2 = -2.0f; ay2 = -2.0f; aarea = 1.0f;
  }
  bool isbest = false;
  for (int k = 0; k < n; ++k) {
    int j = fl[k];           // LDS broadcast (order irrelevant: OR semantics)
    float4 g = gbox[j];
    float iw = fA(fS(fminf(ax2, g.z), fmaxf(ax1, g.x)), 1.0f);
    float ih = fA(fS(fminf(ay2, g.w), fmaxf(ay1, g.y)), 1.0f);
    float inter = fM(fmaxf(iw, 0.0f), fmaxf(ih, 0.0f));
    float uni = fS(fA(aarea, gap[j]), inter);
    float ov = fD(inter, uni);
    if (__float_as_int(ov) == gmb[j]) isbest = true;  // gt_max > 0, ov=0 never matches
  }
  if (isbest && inside) {  // outside rows are -1 in ref, never equal gt_max > 0
    int old = ws->lab8[i];
    if (old != 2) {
      ws->lab8[i] = 2;
      atomicAdd(&ws->hist_fg[bucket_of(rand_fg[i])], 1);
      if (old == 1) atomicSub(&ws->hist_bg[bucket_of(rand_bg[i])], 1);
    }
  }
}

// Find the histogram bucket containing the k-th (0-indexed) smallest value.
// fg/bg totals are derived here from the histogram sums (no count atomics).
__global__ __launch_bounds__(256) void k_scan(Ws* ws) {
  __shared__ int part[256];
  __shared__ int s_fgc;
  int tid = threadIdx.x;
  for (int pass = 0; pass < 2; ++pass) {
    const int* hist = pass == 0 ? ws->hist_fg : ws->hist_bg;
    int sum = 0;
    for (int b = 0; b < NBINS / 256; ++b) sum += hist[tid * (NBINS / 256) + b];
    part[tid] = sum;
    __syncthreads();
    if (tid == 0) {
      int cnt = 0;
      for (int c = 0; c < 256; ++c) cnt += part[c];
      int k, kbg = 0;
      if (pass == 0) {
        s_fgc = cnt;
        ws->fg_count = cnt;
        k = KFG;
      } else {
        ws->bg_count = cnt;
        int kept_fg = s_fgc < KFG ? s_fgc : KFG;
        kbg = BATCH - kept_fg;
        k = kbg;
      }
      if (cnt > k) {  // selection needed; cutoff element is the k-th (0-indexed)
        int cum = 0, chunk = 0;
        for (int c = 0; c < 256; ++c) {
          if (cum + part[c] >= k + 1) { chunk = c; break; }
          cum += part[c];
        }
        int b = chunk * (NBINS / 256);
        for (int bb = chunk * (NBINS / 256); bb < (chunk + 1) * (NBINS / 256); ++bb) {
          if (cum + hist[bb] >= k + 1) { b = bb; break; }
          cum += hist[bb];
        }
        if (pass == 0) { ws->sel_fg = 1; ws->b_fg = b; ws->cb_fg = cum; }
        else           { ws->sel_bg = 1; ws->b_bg = b; ws->cb_bg = cum; }
      } else {
        if (pass == 0) { ws->sel_fg = 0; ws->b_fg = -1; ws->cb_fg = 0; }
        else           { ws->sel_bg = 0; ws->b_bg = -1; ws->cb_bg = 0; }
      }
      if (pass == 1) ws->k_bg = kbg;
    }
    __syncthreads();
  }
}

// Collect boundary-bucket elements (value, index) for exact tie-break ranking.
__global__ __launch_bounds__(256) void k_collect(const float* rand_fg, const float* rand_bg,
                                                 Ws* ws) {
  int i = blockIdx.x * 256 + threadIdx.x;
  int code = ws->lab8[i];
  if (code == 2 && ws->sel_fg) {
    float v = rand_fg[i];
    if (bucket_of(v) == ws->b_fg) {
      int p = atomicAdd(&ws->bnd_fg_n, 1);
      if (p < BCAP) { ws->bnd_fg_val[p] = v; ws->bnd_fg_idx[p] = i; }
    }
  }
  if (code == 1 && ws->sel_bg) {
    float v = rand_bg[i];
    if (bucket_of(v) == ws->b_bg) {
      int p = atomicAdd(&ws->bnd_bg_n, 1);
      if (p < BCAP) { ws->bnd_bg_val[p] = v; ws->bnd_bg_idx[p] = i; }
    }
  }
}

// Exact r-th smallest (value, index) pair within the boundary bucket; weights.
__global__ __launch_bounds__(256) void k_cut(Ws* ws) {
  __shared__ float sv[BCAP];
  __shared__ int si[BCAP];
  int tid = threadIdx.x;
  for (int pass = 0; pass < 2; ++pass) {
    int sel = pass == 0 ? ws->sel_fg : ws->sel_bg;
    if (sel) {
      int n_raw = pass == 0 ? ws->bnd_fg_n : ws->bnd_bg_n;
      int n = n_raw < BCAP ? n_raw : BCAP;
      int r = pass == 0 ? (KFG - ws->cb_fg) : (ws->k_bg - ws->cb_bg);
      const float* bv = pass == 0 ? ws->bnd_fg_val : ws->bnd_bg_val;
      const int* bi = pass == 0 ? ws->bnd_fg_idx : ws->bnd_bg_idx;
      for (int e = tid; e < n; e += 256) { sv[e] = bv[e]; si[e] = bi[e]; }
      __syncthreads();
      if (r >= 0 && r < n) {
        for (int e = tid; e < n; e += 256) {
          float ve = sv[e]; int ie = si[e];
          int c = 0;
          for (int o = 0; o < n; ++o) {
            float vo = sv[o]; int io = si[o];
            if (vo < ve || (vo == ve && io < ie)) c++;
          }
          if (c == r) {  // exactly one element has lexicographic rank r
            if (pass == 0) { ws->cut_fg_val = ve; ws->cut_fg_idx = ie; }
            else           { ws->cut_bg_val = ve; ws->cut_bg_idx = ie; }
          }
        }
      }
      __syncthreads();
    }
  }
  if (tid == 0) {
    int kept_fg = ws->sel_fg ? KFG : ws->fg_count;
    int kept_bg = ws->sel_bg ? ws->k_bg : ws->bg_count;
    int ne = kept_fg + kept_bg;
    ws->wgt = (ne > 0) ? __fdiv_rn(1.0f, (float)(ne < 1 ? 1 : ne)) : 0.0f;
  }
}

// Apply subsampling cutoffs; assemble all 7 output columns and write the
// (T,7) AoS rows via LDS transpose -> 7 fully-coalesced wave stores per block.
__global__ __launch_bounds__(256) void k_final(const float* rand_fg, const float* rand_bg,
                                               const Ws* __restrict__ ws, float* out) {
  __shared__ float sh[256][8];  // +1 pad col to break bank alignment
  int tid = threadIdx.x;
  int i0 = blockIdx.x * 256;
  int i = i0 + tid;
  int code = ws->lab8[i];
  float lab = code == 2 ? 1.0f : (code == 1 ? 0.0f : -1.0f);
  if (code == 2 && ws->sel_fg) {
    float v = rand_fg[i];
    int b = bucket_of(v);
    float cv = ws->cut_fg_val; int ci = ws->cut_fg_idx;
    bool keep = (b < ws->b_fg) ||
                (b == ws->b_fg && (v < cv || (v == cv && i < ci)));
    if (!keep) lab = -1.0f;
  }
  if (code == 1 && ws->sel_bg) {
    float v = rand_bg[i];
    int b = bucket_of(v);
    float cv = ws->cut_bg_val; int ci = ws->cut_bg_idx;
    bool keep = (b < ws->b_bg) ||
                (b == ws->b_bg && (v < cv || (v == cv && i < ci)));
    if (!keep) lab = -1.0f;
  }
  sh[tid][0] = lab;
  sh[tid][1] = ws->t_soa[0][i];
  sh[tid][2] = ws->t_soa[1][i];
  sh[tid][3] = ws->t_soa[2][i];
  sh[tid][4] = ws->t_soa[3][i];
  sh[tid][5] = (lab == 1.0f) ? 1.0f : 0.0f;
  sh[tid][6] = (lab >= 0.0f) ? ws->wgt : 0.0f;
  __syncthreads();
#pragma unroll
  for (int k = 0; k < 7; ++k) {
    int l = k * 256 + tid;
    out[i0 * 7 + l] = sh[l / 7][l % 7];
  }
}

extern "C" void kernel_launch(void* const* d_in, const int* in_sizes, int n_in,
                              void* d_out, int out_size, void* d_ws, size_t ws_size,
                              hipStream_t stream) {
  const float* gt   = (const float*)d_in[1];
  const float* im   = (const float*)d_in[2];
  const float* anch = (const float*)d_in[3];
  const float* rfg  = (const float*)d_in[4];
  const float* rbg  = (const float*)d_in[5];
  const int*   fs   = (const int*)d_in[6];
  float* out = (float*)d_out;
  Ws* ws = (Ws*)d_ws;

  dim3 blk(256);
  k_init<<<17, blk, 0, stream>>>(gt, anch, ws);
  k_sweep<<<NB_, blk, 0, stream>>>(ws->g_box, ws->g_area, ws->amm, im, anch, fs,
                                   rfg, rbg, ws->blk_max, ws);
  k_reduce<<<M_, 64, 0, stream>>>(ws->blk_max, ws->gt_max_bits);
  k_fixup<<<NB_, blk, 0, stream>>>(ws->g_box, ws->g_area, ws->gt_max_bits, ws->blk_max,
                                   im, anch, fs, rfg, rbg, ws);
  k_scan<<<1, blk, 0, stream>>>(ws);
  k_collect<<<NB_, blk, 0, stream>>>(rfg, rbg, ws);
  k_cut<<<1, blk, 0, stream>>>(ws);
  k_final<<<NB_, blk, 0, stream>>>(rfg, rbg, ws, out);
}